// Round 1
// 423.673 us; speedup vs baseline: 1.0225x; 1.0225x over previous
//
#include <hip/hip_runtime.h>
#include <cstdint>

typedef unsigned short u16;
typedef short s16x8 __attribute__((ext_vector_type(8)));
typedef float f32x4 __attribute__((ext_vector_type(4)));
typedef float f32x16 __attribute__((ext_vector_type(16)));

__device__ __forceinline__ u16 f2bf(float x) {
  uint32_t u = __builtin_bit_cast(uint32_t, x);
  u += 0x7FFFu + ((u >> 16) & 1u);   // RTNE
  return (u16)(u >> 16);
}
__device__ __forceinline__ float bf2f(u16 v) {
  return __builtin_bit_cast(float, (uint32_t)v << 16);
}
__device__ __forceinline__ uint32_t pk_bf16(float lo, float hi) {
  uint32_t ul = __builtin_bit_cast(uint32_t, lo);
  uint32_t uh = __builtin_bit_cast(uint32_t, hi);
  ul += 0x7FFFu + ((ul >> 16) & 1u);
  uh += 0x7FFFu + ((uh >> 16) & 1u);
  return __builtin_amdgcn_perm(uh, ul, 0x07060302u);
}
__device__ __forceinline__ f32x4 mfma16(s16x8 a, s16x8 b, f32x4 c) {
  return __builtin_amdgcn_mfma_f32_16x16x32_bf16(a, b, c, 0, 0, 0);
}
__device__ __forceinline__ f32x16 mfma32(s16x8 a, s16x8 b, f32x16 c) {
  return __builtin_amdgcn_mfma_f32_32x32x16_bf16(a, b, c, 0, 0, 0);
}
__device__ __forceinline__ s16x8 ld_frag(const u16* p) {
  uint4 v = *(const uint4*)p;
  return __builtin_bit_cast(s16x8, v);
}
__device__ __forceinline__ s16x8 ld_frag_lds(const u16* p) {
  uint4 v = *(const uint4*)p;
  return __builtin_bit_cast(s16x8, v);
}

// ---------------- kernel 1: W fp32 -> bf16, MFMA-fragment-linear order -----
__global__ void prep_w(const float* __restrict__ Wq, const float* __restrict__ Wkv,
                       u16* __restrict__ wqs, u16* __restrict__ wkvs) {
  int tid = blockIdx.x * 256 + threadIdx.x;        // 0 .. 13823
  if (tid >= 13824) return;
  bool isQ = tid < 4608;                           // Q: 12 fb * 6 kk * 64 lanes
  int id = isQ ? tid : tid - 4608;                 // KV: 24 fb * 6 kk * 64 lanes
  int lane = id & 63, fk = id >> 6;
  int kk = fk % 6, fb = fk / 6;
  int f = fb * 16 + (lane & 15), k0 = kk * 32 + ((lane >> 4) << 3);
  const float* src = (isQ ? Wq : Wkv) + (size_t)f * 192 + k0;
  const float sc = isQ ? 0.17677669529663687f : 1.0f;   // 1/sqrt(32) folded into Wq
  float4 a = ((const float4*)src)[0], b = ((const float4*)src)[1];
  uint4 o;
  o.x = pk_bf16(a.x * sc, a.y * sc); o.y = pk_bf16(a.z * sc, a.w * sc);
  o.z = pk_bf16(b.x * sc, b.y * sc); o.w = pk_bf16(b.z * sc, b.w * sc);
  *(uint4*)&(isQ ? wqs : wkvs)[(size_t)id * 8] = o;
}

// ---------------- kernel 2: rpb[h][q][n] = bf16(table[rpi[q][n]][h]) -------
__global__ void build_rpb(const int* __restrict__ rpi, const float* __restrict__ table,
                          u16* __restrict__ rpb) {
  int q = blockIdx.x, n = threadIdx.x;             // grid 256 x block 576
  int idx = rpi[q * 576 + n] * 6;
#pragma unroll
  for (int hh = 0; hh < 6; ++hh)
    rpb[(size_t)hh * 147456 + q * 576 + n] = f2bf(table[idx + hh]);
}

// ---------------- kernel 3: merged projection GEMM (Q + KV in one grid) ----
// NEW this round: A-tile (64 rows x 192 f32) staged through LDS with fully
// coalesced global loads (thread t reads row t>>2, 64B-aligned chunks), bf16
// converted once, LDS row stride 200 u16 (=400B=100 dw) so the fragment
// ds_read_b128 spreads uniformly over all 32 banks. Previous version issued
// per-lane float4 loads at 768B lane stride (zero coalescing) -> proj_all was
// latency-bound at 6.9% MfmaUtil / 18% HBM.
#define LDA 200
template <int NC, int MODE>
__device__ __forceinline__ void proj_body(const float* __restrict__ A,
                                          const u16* __restrict__ W,
                                          u16* __restrict__ outQ, u16* __restrict__ outK,
                                          u16* __restrict__ outV, int blk,
                                          u16* __restrict__ lA) {
  const int t = threadIdx.x, lane = t & 63, w = t >> 6, c = lane & 15, hi = lane >> 4;
  const int mbase0 = blk << 6;
  // ---- coalesced A stage: row = t>>2, 4 threads cover 192 floats of a row
  {
    const int row = t >> 2, cq = t & 3;
    const float* src = A + (size_t)(mbase0 + row) * 192 + (cq << 2);
    u16* dst = lA + row * LDA + (cq << 2);
#pragma unroll
    for (int i = 0; i < 12; ++i) {                 // cols cq*4 + 16*i .. +3
      float4 v = *(const float4*)(src + (i << 4));
      uint2 p;
      p.x = pk_bf16(v.x, v.y);
      p.y = pk_bf16(v.z, v.w);
      *(uint2*)(dst + (i << 4)) = p;
    }
  }
  __syncthreads();
  s16x8 af[6];                                     // this wave's 16 x-rows
  const u16* lrow = lA + (w * 16 + c) * LDA;
#pragma unroll
  for (int kk = 0; kk < 6; ++kk)
    af[kk] = ld_frag_lds(lrow + (kk << 5) + (hi << 3));

  s16x8 wf[4], wfn[4];
#pragma unroll
  for (int nb = 0; nb < 4; ++nb)                   // prologue: (nc=0, kk=0)
    wf[nb] = ld_frag(&W[(((size_t)(nb * 6) << 6) + lane) << 3]);
#pragma unroll
  for (int nc = 0; nc < NC; ++nc) {
    f32x4 acc[4];
#pragma unroll
    for (int nb = 0; nb < 4; ++nb) acc[nb] = f32x4{0.f, 0.f, 0.f, 0.f};
#pragma unroll
    for (int kk = 0; kk < 6; ++kk) {
      const int nnc = (kk == 5) ? nc + 1 : nc, nkk = (kk == 5) ? 0 : kk + 1;
      if (nnc < NC) {
#pragma unroll
        for (int nb = 0; nb < 4; ++nb)
          wfn[nb] = ld_frag(&W[(((size_t)(((nnc << 2) + nb) * 6 + nkk) << 6) + lane) << 3]);
      }
#pragma unroll
      for (int nb = 0; nb < 4; ++nb) acc[nb] = mfma16(wf[nb], af[kk], acc[nb]);
#pragma unroll
      for (int nb = 0; nb < 4; ++nb) wf[nb] = wfn[nb];
    }
    const int m = mbase0 + (w << 4) + c;
#pragma unroll
    for (int nb = 0; nb < 4; ++nb) {
      int fb = (nc << 6) + (nb << 4) + (hi << 2);
      uint2 pv;
      pv.x = pk_bf16(acc[nb][0], acc[nb][1]);
      pv.y = pk_bf16(acc[nb][2], acc[nb][3]);
      if (MODE == 0) {
        int b = m >> 8, q = m & 255, hh = fb >> 5, d = fb & 31;
        *(uint2*)&outQ[((((size_t)(b * 6 + hh)) << 8) + q) * 32 + d] = pv;
      } else {
        int b = m / 576, tok = m - b * 576;
        int f2 = fb; u16* dst = outK;
        if (f2 >= 192) { dst = outV; f2 -= 192; }
        int hh = f2 >> 5, d = f2 & 31;
        *(uint2*)&dst[(((size_t)(b * 6 + hh)) * 576 + tok) * 32 + d] = pv;
      }
    }
  }
}

__launch_bounds__(256)
__global__ void proj_all(const float* __restrict__ xq, const float* __restrict__ xkv,
                         const u16* __restrict__ wqs, const u16* __restrict__ wkvs,
                         u16* __restrict__ Qws, u16* __restrict__ Kws,
                         u16* __restrict__ Vws) {
  __shared__ __align__(16) u16 lA[64 * LDA];       // 25.6 KB
  int blk = blockIdx.x;
  if (blk < 1024) proj_body<3, 0>(xq, wqs, Qws, nullptr, nullptr, blk, lA);
  else            proj_body<6, 1>(xkv, wkvs, nullptr, Kws, Vws, blk - 1024, lA);
}

// ---------------- kernel 4: fused attention, depth-2 K/bias pipeline -------
// Identical math to R4 (verified). K + bias register-prefetched 2 kt
// ahead (12 loads in flight, breaks the depth-1 convoy); Vt ds_reads hoisted
// to the top of the body so LDS latency overlaps the exp chain.
#define VSTR 600
__launch_bounds__(512)
__global__ void attn(const u16* __restrict__ Qws, const u16* __restrict__ Kws,
                     const u16* __restrict__ Vws, const u16* __restrict__ rpb,
                     float* __restrict__ out) {
  __shared__ __align__(16) u16 Vt[32 * VSTR];
  const int bh = blockIdx.x, b = bh / 6, h = bh - b * 6;
  const size_t kvbase = (size_t)bh * 576 * 32;
  const int t = threadIdx.x;
  for (int key = t; key < 576; key += 512) {       // stage V permuted (R4-verified)
    int kk = key & 31, k15 = kk & 15;
    int p = ((kk >> 4) << 4) | (((k15 >> 2) & 1) << 3) | ((k15 >> 3) << 2) | (k15 & 3);
    int col = ((key >> 5) << 5) + p;
    const uint4* src = (const uint4*)&Vws[kvbase + (size_t)key * 32];
    uint4 r[4] = {src[0], src[1], src[2], src[3]};
    const u16* vs = (const u16*)r;
#pragma unroll
    for (int d = 0; d < 32; ++d) Vt[d * VSTR + col] = vs[d];
  }
  const int lane = t & 63, l31 = lane & 31, u = lane >> 5, w = t >> 6;
  const int qg = (w << 5) + l31;
  s16x8 qf[2];
#pragma unroll
  for (int m = 0; m < 2; ++m)
    qf[m] = ld_frag(&Qws[((size_t)bh * 256 + qg) * 32 + (m << 4) + (u << 3)]);
  __syncthreads();
  f32x16 oacc;
#pragma unroll
  for (int r = 0; r < 16; ++r) oacc[r] = 0.f;
  float psum = 0.f;
  const u16* rpbq = rpb + (size_t)h * 147456 + (size_t)qg * 576;
  const size_t krow = kvbase + (size_t)l31 * 32 + (u << 3);
  // depth-2 pipeline: buffers for kt and kt+1
  s16x8 kA[2], kB[2];
  ushort4 bb[2][4];
  kA[0] = ld_frag(&Kws[krow]);        kB[0] = ld_frag(&Kws[krow + 16]);
  kA[1] = ld_frag(&Kws[krow + 1024]); kB[1] = ld_frag(&Kws[krow + 1024 + 16]);
#pragma unroll
  for (int g = 0; g < 4; ++g) {
    bb[0][g] = *(const ushort4*)&rpbq[(g << 3) + (u << 2)];
    bb[1][g] = *(const ushort4*)&rpbq[32 + (g << 3) + (u << 2)];
  }
#pragma unroll 2
  for (int kt = 0; kt < 18; ++kt) {
    const int k0 = kt << 5, cur = kt & 1;
    // hoisted LDS reads for this kt (no deps -> overlap exp chain)
    s16x8 vf0 = ld_frag(&Vt[l31 * VSTR + k0 + (u << 3)]);
    s16x8 vf1 = ld_frag(&Vt[l31 * VSTR + k0 + 16 + (u << 3)]);
    f32x16 st;
#pragma unroll
    for (int r = 0; r < 16; ++r) st[r] = 0.f;
    st = mfma32(kA[cur], qf[0], st);               // d = 0..15
    st = mfma32(kB[cur], qf[1], st);               // d = 16..31
    ushort4 bc[4] = {bb[cur][0], bb[cur][1], bb[cur][2], bb[cur][3]};
    if (kt < 16) {                                 // prefetch kt+2
      const size_t kb = krow + (size_t)(k0 + 64) * 32;
      kA[cur] = ld_frag(&Kws[kb]);
      kB[cur] = ld_frag(&Kws[kb + 16]);
#pragma unroll
      for (int g = 0; g < 4; ++g)
        bb[cur][g] = *(const ushort4*)&rpbq[k0 + 64 + (g << 3) + (u << 2)];
    }
    float e[16];
#pragma unroll
    for (int g = 0; g < 4; ++g) {
      const u16* bp = (const u16*)&bc[g];
#pragma unroll
      for (int c3 = 0; c3 < 4; ++c3) {
        int r = (g << 2) + c3;
        e[r] = __expf(st[r] + bf2f(bp[c3]));       // key = 8g + 4u + c3
      }
    }
    psum += (((e[0] + e[1]) + (e[2] + e[3])) + ((e[4] + e[5]) + (e[6] + e[7]))) +
            (((e[8] + e[9]) + (e[10] + e[11])) + ((e[12] + e[13]) + (e[14] + e[15])));
    uint4 pa, pb;
    pa.x = pk_bf16(e[0], e[1]);   pa.y = pk_bf16(e[2], e[3]);
    pa.z = pk_bf16(e[4], e[5]);   pa.w = pk_bf16(e[6], e[7]);
    pb.x = pk_bf16(e[8], e[9]);   pb.y = pk_bf16(e[10], e[11]);
    pb.z = pk_bf16(e[12], e[13]); pb.w = pk_bf16(e[14], e[15]);
    s16x8 pf0 = __builtin_bit_cast(s16x8, pa);
    s16x8 pf1 = __builtin_bit_cast(s16x8, pb);
    oacc = mfma32(vf0, pf0, oacc);
    oacc = mfma32(vf1, pf1, oacc);
  }
  float tot = psum + __shfl_xor(psum, 32);
  float rs = 1.0f / tot;
  float* op = out + ((size_t)b * 256 + qg) * 192 + h * 32 + (u << 2);
#pragma unroll
  for (int g = 0; g < 4; ++g) {
    float4 o;
    o.x = oacc[(g << 2) + 0] * rs; o.y = oacc[(g << 2) + 1] * rs;
    o.z = oacc[(g << 2) + 2] * rs; o.w = oacc[(g << 2) + 3] * rs;
    *(float4*)(op + (g << 3)) = o;
  }
}

// ---------------- launcher -------------------------------------------------
extern "C" void kernel_launch(void* const* d_in, const int* in_sizes, int n_in,
                              void* d_out, int out_size, void* d_ws, size_t ws_size,
                              hipStream_t stream) {
  const float* x_q   = (const float*)d_in[0];
  const float* x_kv  = (const float*)d_in[1];
  const int*   rpi   = (const int*)d_in[2];
  const float* Wq    = (const float*)d_in[3];
  const float* Wkv   = (const float*)d_in[4];
  const float* table = (const float*)d_in[5];
  float* out = (float*)d_out;

  char* ws = (char*)d_ws;
  u16* wqs  = (u16*)(ws);                          //    73,728 B (swizzled)
  u16* wkvs = (u16*)(ws + 73728);                  //   147,456 B (swizzled)
  u16* rpb  = (u16*)(ws + 221184);                 // 1,769,472 B
  u16* Qws  = (u16*)(ws + 1990656);                // 25,165,824 B
  u16* Kws  = (u16*)(ws + 27156480);               // 56,623,104 B
  u16* Vws  = (u16*)(ws + 83779584);               // 56,623,104 B  (total ~134 MB)

  prep_w<<<54, 256, 0, stream>>>(Wq, Wkv, wqs, wkvs);
  build_rpb<<<256, 576, 0, stream>>>(rpi, table, rpb);
  proj_all<<<3328, 256, 0, stream>>>(x_q, x_kv, wqs, wkvs, Qws, Kws, Vws);
  attn<<<1536, 512, 0, stream>>>(Qws, Kws, Vws, rpb, out);
}

// Round 2
// 348.129 us; speedup vs baseline: 1.2444x; 1.2170x over previous
//
#include <hip/hip_runtime.h>
#include <cstdint>

typedef unsigned short u16;
typedef short s16x8 __attribute__((ext_vector_type(8)));
typedef float f32x4 __attribute__((ext_vector_type(4)));
typedef float f32x16 __attribute__((ext_vector_type(16)));

#if __has_builtin(__builtin_amdgcn_exp2f)
#define EXP2(x) __builtin_amdgcn_exp2f(x)
#else
#define EXP2(x) __expf((x)*0.6931471805599453f)
#endif

__device__ __forceinline__ u16 f2bf(float x) {
  uint32_t u = __builtin_bit_cast(uint32_t, x);
  u += 0x7FFFu + ((u >> 16) & 1u);   // RTNE
  return (u16)(u >> 16);
}
__device__ __forceinline__ float bf2f(u16 v) {
  return __builtin_bit_cast(float, (uint32_t)v << 16);
}
__device__ __forceinline__ uint32_t pk_bf16(float lo, float hi) {
  uint32_t ul = __builtin_bit_cast(uint32_t, lo);
  uint32_t uh = __builtin_bit_cast(uint32_t, hi);
  ul += 0x7FFFu + ((ul >> 16) & 1u);
  uh += 0x7FFFu + ((uh >> 16) & 1u);
  return __builtin_amdgcn_perm(uh, ul, 0x07060302u);
}
__device__ __forceinline__ f32x4 mfma16(s16x8 a, s16x8 b, f32x4 c) {
  return __builtin_amdgcn_mfma_f32_16x16x32_bf16(a, b, c, 0, 0, 0);
}
__device__ __forceinline__ f32x16 mfma32(s16x8 a, s16x8 b, f32x16 c) {
  return __builtin_amdgcn_mfma_f32_32x32x16_bf16(a, b, c, 0, 0, 0);
}
__device__ __forceinline__ s16x8 ld_frag(const u16* p) {
  uint4 v = *(const uint4*)p;
  return __builtin_bit_cast(s16x8, v);
}

// ---------------- kernel 1: W fp32 -> bf16, MFMA-fragment-linear order -----
// Q scale = 1/sqrt(32) * log2(e)  (exp -> exp2 fold, see attn)
__global__ void prep_w(const float* __restrict__ Wq, const float* __restrict__ Wkv,
                       u16* __restrict__ wqs, u16* __restrict__ wkvs) {
  int tid = blockIdx.x * 256 + threadIdx.x;        // 0 .. 13823
  if (tid >= 13824) return;
  bool isQ = tid < 4608;                           // Q: 12 fb * 6 kk * 64 lanes
  int id = isQ ? tid : tid - 4608;                 // KV: 24 fb * 6 kk * 64 lanes
  int lane = id & 63, fk = id >> 6;
  int kk = fk % 6, fb = fk / 6;
  int f = fb * 16 + (lane & 15), k0 = kk * 32 + ((lane >> 4) << 3);
  const float* src = (isQ ? Wq : Wkv) + (size_t)f * 192 + k0;
  const float sc = isQ ? 0.2550348583f : 1.0f;     // (1/sqrt(32))*log2e
  float4 a = ((const float4*)src)[0], b = ((const float4*)src)[1];
  uint4 o;
  o.x = pk_bf16(a.x * sc, a.y * sc); o.y = pk_bf16(a.z * sc, a.w * sc);
  o.z = pk_bf16(b.x * sc, b.y * sc); o.w = pk_bf16(b.z * sc, b.w * sc);
  *(uint4*)&(isQ ? wqs : wkvs)[(size_t)id * 8] = o;
}

// ---------------- kernel 2: rpb2[h][n][q] = bf16(log2e * table[rpi[q][n]][h])
// TRANSPOSED vs prior round: [h][key][q] so attn's bias reads are q-contiguous
// across lanes (2 cache lines per wave-load instead of 64).
__global__ void build_rpb(const int* __restrict__ rpi, const float* __restrict__ table,
                          u16* __restrict__ rpb) {
  int n = blockIdx.x, q = threadIdx.x;             // grid 576 x block 256
  int idx = rpi[q * 576 + n] * 6;                  // scattered read, L2-resident
#pragma unroll
  for (int hh = 0; hh < 6; ++hh)
    rpb[(size_t)hh * 147456 + n * 256 + q] = f2bf(table[idx + hh] * 1.4426950409f);
}

// ---------------- kernel 3: merged projection GEMM (Q + KV in one grid) ----
// A staged via LDS (coalesced, R1-verified). NEW: depth-2 rolling W prefetch
// (8 16B loads in flight per wave; depth-1 convoy was the 6.9%-MfmaUtil stall)
// and K written in attn-fragment-linear order (see attn for layout algebra).
#define LDA 200
template <int NC, int MODE>
__device__ __forceinline__ void proj_body(const float* __restrict__ A,
                                          const u16* __restrict__ W,
                                          u16* __restrict__ outQ, u16* __restrict__ outK,
                                          u16* __restrict__ outV, int blk,
                                          u16* __restrict__ lA) {
  const int t = threadIdx.x, lane = t & 63, w = t >> 6, c = lane & 15, hi = lane >> 4;
  const int mbase0 = blk << 6;
  // ---- coalesced A stage: row = t>>2, 4 threads cover 192 floats of a row
  {
    const int row = t >> 2, cq = t & 3;
    const float* src = A + (size_t)(mbase0 + row) * 192 + (cq << 2);
    u16* dst = lA + row * LDA + (cq << 2);
#pragma unroll
    for (int i = 0; i < 12; ++i) {                 // cols cq*4 + 16*i .. +3
      float4 v = *(const float4*)(src + (i << 4));
      uint2 p;
      p.x = pk_bf16(v.x, v.y);
      p.y = pk_bf16(v.z, v.w);
      *(uint2*)(dst + (i << 4)) = p;
    }
  }
  __syncthreads();
  s16x8 af[6];                                     // this wave's 16 x-rows
  const u16* lrow = lA + (w * 16 + c) * LDA;
#pragma unroll
  for (int kk = 0; kk < 6; ++kk)
    af[kk] = ld_frag(lrow + (kk << 5) + (hi << 3));

  constexpr int TOT = NC * 6;
  const int m = mbase0 + (w << 4) + c;
  s16x8 w0[4], w1[4], w2[4];
#pragma unroll
  for (int nb = 0; nb < 4; ++nb)
    w0[nb] = ld_frag(&W[((size_t)((nb * 6) * 64 + lane)) * 8]);
#pragma unroll
  for (int nb = 0; nb < 4; ++nb)
    w1[nb] = ld_frag(&W[((size_t)((nb * 6 + 1) * 64 + lane)) * 8]);
  f32x4 acc[4];
#pragma unroll
  for (int nb = 0; nb < 4; ++nb) acc[nb] = f32x4{0.f, 0.f, 0.f, 0.f};
#pragma unroll
  for (int s = 0; s < TOT; ++s) {
    const int nc = s / 6, kk = s % 6;              // compile-time (full unroll)
    if (s + 2 < TOT) {
      const int nc2 = (s + 2) / 6, kk2 = (s + 2) % 6;
#pragma unroll
      for (int nb = 0; nb < 4; ++nb)
        w2[nb] = ld_frag(&W[((size_t)((((nc2 << 2) + nb) * 6 + kk2) * 64 + lane)) * 8]);
    }
#pragma unroll
    for (int nb = 0; nb < 4; ++nb) acc[nb] = mfma16(w0[nb], af[kk], acc[nb]);
    if (kk == 5) {
#pragma unroll
      for (int nb = 0; nb < 4; ++nb) {
        int fb = (nc << 6) + (nb << 4) + (hi << 2);
        uint2 pv;
        pv.x = pk_bf16(acc[nb][0], acc[nb][1]);
        pv.y = pk_bf16(acc[nb][2], acc[nb][3]);
        if (MODE == 0) {
          int b = m >> 8, q = m & 255, hh = fb >> 5, d = fb & 31;
          *(uint2*)&outQ[((((size_t)(b * 6 + hh)) << 8) + q) * 32 + d] = pv;
        } else {
          int b = m / 576, tok = m - b * 576;
          if (fb >= 192) {                         // V: layout unchanged
            int f2 = fb - 192, hh = f2 >> 5, d = f2 & 31;
            *(uint2*)&outV[(((size_t)(b * 6 + hh)) * 576 + tok) * 32 + d] = pv;
          } else {                                 // K: fragment-linear for attn
            int hh = fb >> 5, dd = fb & 31;        // dd = (nb&1)*16 + hi*4
            int half = dd >> 4, uu = (dd >> 3) & 1, e0 = dd & 7;
            int kt = tok >> 5, lt = tok & 31;
            *(uint2*)&outK[(size_t)((b * 6 + hh) * 18 + kt) * 1024 +
                           half * 512 + uu * 256 + lt * 8 + e0] = pv;
          }
        }
        acc[nb] = f32x4{0.f, 0.f, 0.f, 0.f};
      }
    }
#pragma unroll
    for (int nb = 0; nb < 4; ++nb) { w0[nb] = w1[nb]; w1[nb] = w2[nb]; }
  }
}

__launch_bounds__(256)
__global__ void proj_all(const float* __restrict__ xq, const float* __restrict__ xkv,
                         const u16* __restrict__ wqs, const u16* __restrict__ wkvs,
                         u16* __restrict__ Qws, u16* __restrict__ Kws,
                         u16* __restrict__ Vws) {
  __shared__ __align__(16) u16 lA[64 * LDA];       // 25.6 KB
  int blk = blockIdx.x;
  if (blk < 1024) proj_body<3, 0>(xq, wqs, Qws, nullptr, nullptr, blk, lA);
  else            proj_body<6, 1>(xkv, wkvs, nullptr, Kws, Vws, blk - 1024, lA);
}

// ---------------- kernel 4: fused attention ---------------------------------
// NEW: K loads are fragment-linear (1 KB contiguous per wave-load, was a
// 32-line gather) and bias loads hit the transposed rpb2[h][key][q] (2 lines
// per wave-load, was 64). exp -> native v_exp_f32 via exp2 fold.
#define VSTR 600
__launch_bounds__(512)
__global__ void attn(const u16* __restrict__ Qws, const u16* __restrict__ Kws,
                     const u16* __restrict__ Vws, const u16* __restrict__ rpb,
                     float* __restrict__ out) {
  __shared__ __align__(16) u16 Vt[32 * VSTR];
  const int bh = blockIdx.x, b = bh / 6, h = bh - b * 6;
  const size_t kvbase = (size_t)bh * 576 * 32;     // V only
  const int t = threadIdx.x;
  for (int key = t; key < 576; key += 512) {       // stage V permuted (verified)
    int kk = key & 31, k15 = kk & 15;
    int p = ((kk >> 4) << 4) | (((k15 >> 2) & 1) << 3) | ((k15 >> 3) << 2) | (k15 & 3);
    int col = ((key >> 5) << 5) + p;
    const uint4* src = (const uint4*)&Vws[kvbase + (size_t)key * 32];
    uint4 r[4] = {src[0], src[1], src[2], src[3]};
    const u16* vs = (const u16*)r;
#pragma unroll
    for (int d = 0; d < 32; ++d) Vt[d * VSTR + col] = vs[d];
  }
  const int lane = t & 63, l31 = lane & 31, u = lane >> 5, w = t >> 6;
  const int qg = (w << 5) + l31;
  s16x8 qf[2];
#pragma unroll
  for (int m = 0; m < 2; ++m)
    qf[m] = ld_frag(&Qws[((size_t)bh * 256 + qg) * 32 + (m << 4) + (u << 3)]);
  __syncthreads();
  f32x16 oacc;
#pragma unroll
  for (int r = 0; r < 16; ++r) oacc[r] = 0.f;
  float psum = 0.f;
  // K fragment-linear: per kt, kA at kfb + kt*1024, kB at +512 (u16 units)
  const u16* kfb = Kws + (size_t)bh * 18432 + (size_t)lane * 8;
  // bias: rpb2[h][key][q]; key = kt*32 + 8g + 4u + c3, q = qg
  const u16* bpu = rpb + (size_t)h * 147456 + ((size_t)u << 10) + qg;
  s16x8 kA[2], kB[2];
  ushort bb[2][16];
  kA[0] = ld_frag(kfb);        kB[0] = ld_frag(kfb + 512);
  kA[1] = ld_frag(kfb + 1024); kB[1] = ld_frag(kfb + 1536);
#pragma unroll
  for (int r = 0; r < 16; ++r) {
    const int C = ((r >> 2) << 3) + (r & 3);       // key offset (minus 4u)
    bb[0][r] = bpu[(size_t)C << 8];
    bb[1][r] = bpu[(size_t)(32 + C) << 8];
  }
#pragma unroll 2
  for (int kt = 0; kt < 18; ++kt) {
    const int k0 = kt << 5, cur = kt & 1;          // cur compile-time (unroll 2)
    s16x8 vf0 = ld_frag(&Vt[l31 * VSTR + k0 + (u << 3)]);
    s16x8 vf1 = ld_frag(&Vt[l31 * VSTR + k0 + 16 + (u << 3)]);
    f32x16 st;
#pragma unroll
    for (int r = 0; r < 16; ++r) st[r] = 0.f;
    st = mfma32(kA[cur], qf[0], st);               // d = 0..15
    st = mfma32(kB[cur], qf[1], st);               // d = 16..31
    ushort bc[16];
#pragma unroll
    for (int r = 0; r < 16; ++r) bc[r] = bb[cur][r];
    if (kt < 16) {                                 // prefetch kt+2
      kA[cur] = ld_frag(kfb + (size_t)(kt + 2) * 1024);
      kB[cur] = ld_frag(kfb + (size_t)(kt + 2) * 1024 + 512);
#pragma unroll
      for (int r = 0; r < 16; ++r) {
        const int C = ((r >> 2) << 3) + (r & 3);
        bb[cur][r] = bpu[(size_t)((kt + 2) * 32 + C) << 8];
      }
    }
    float e[16];
#pragma unroll
    for (int r = 0; r < 16; ++r)
      e[r] = EXP2(st[r] + bf2f(bc[r]));            // key-row = 8g+4u+c3 (verified map)
    psum += (((e[0] + e[1]) + (e[2] + e[3])) + ((e[4] + e[5]) + (e[6] + e[7]))) +
            (((e[8] + e[9]) + (e[10] + e[11])) + ((e[12] + e[13]) + (e[14] + e[15])));
    uint4 pa, pb;
    pa.x = pk_bf16(e[0], e[1]);   pa.y = pk_bf16(e[2], e[3]);
    pa.z = pk_bf16(e[4], e[5]);   pa.w = pk_bf16(e[6], e[7]);
    pb.x = pk_bf16(e[8], e[9]);   pb.y = pk_bf16(e[10], e[11]);
    pb.z = pk_bf16(e[12], e[13]); pb.w = pk_bf16(e[14], e[15]);
    s16x8 pf0 = __builtin_bit_cast(s16x8, pa);
    s16x8 pf1 = __builtin_bit_cast(s16x8, pb);
    oacc = mfma32(vf0, pf0, oacc);
    oacc = mfma32(vf1, pf1, oacc);
  }
  float tot = psum + __shfl_xor(psum, 32);
  float rs = 1.0f / tot;
  float* op = out + ((size_t)b * 256 + qg) * 192 + h * 32 + (u << 2);
#pragma unroll
  for (int g = 0; g < 4; ++g) {
    float4 o;
    o.x = oacc[(g << 2) + 0] * rs; o.y = oacc[(g << 2) + 1] * rs;
    o.z = oacc[(g << 2) + 2] * rs; o.w = oacc[(g << 2) + 3] * rs;
    *(float4*)(op + (g << 3)) = o;
  }
}

// ---------------- launcher -------------------------------------------------
extern "C" void kernel_launch(void* const* d_in, const int* in_sizes, int n_in,
                              void* d_out, int out_size, void* d_ws, size_t ws_size,
                              hipStream_t stream) {
  const float* x_q   = (const float*)d_in[0];
  const float* x_kv  = (const float*)d_in[1];
  const int*   rpi   = (const int*)d_in[2];
  const float* Wq    = (const float*)d_in[3];
  const float* Wkv   = (const float*)d_in[4];
  const float* table = (const float*)d_in[5];
  float* out = (float*)d_out;

  char* ws = (char*)d_ws;
  u16* wqs  = (u16*)(ws);                          //    73,728 B (swizzled)
  u16* wkvs = (u16*)(ws + 73728);                  //   147,456 B (swizzled)
  u16* rpb  = (u16*)(ws + 221184);                 // 1,769,472 B  [h][key][q]
  u16* Qws  = (u16*)(ws + 1990656);                // 25,165,824 B
  u16* Kws  = (u16*)(ws + 27156480);               // 56,623,104 B (frag-linear)
  u16* Vws  = (u16*)(ws + 83779584);               // 56,623,104 B  (total ~134 MB)

  prep_w<<<54, 256, 0, stream>>>(Wq, Wkv, wqs, wkvs);
  build_rpb<<<576, 256, 0, stream>>>(rpi, table, rpb);
  proj_all<<<3328, 256, 0, stream>>>(x_q, x_kv, wqs, wkvs, Qws, Kws, Vws);
  attn<<<1536, 512, 0, stream>>>(Qws, Kws, Vws, rpb, out);
}